// Round 7
// baseline (620.479 us; speedup 1.0000x reference)
//
#include <hip/hip_runtime.h>
#include <hip/hip_bf16.h>

// Problem dims
#define BB 8
#define SS 1024
#define DD 1152
#define HH 16
#define HD 72
#define PD 96          // padded head dim inside attention MFMA only
#define LL 32
#define RR 36
#define NTOK (BB*SS)   // 8192

typedef __attribute__((ext_vector_type(8)))  short short8;
typedef __attribute__((ext_vector_type(4)))  float f32x4;
typedef __attribute__((ext_vector_type(16))) float f32x16;
typedef __attribute__((ext_vector_type(4)))  unsigned short ushort4v;

// ---------- workspace layout ----------
#define F_IAT   0        // 1024
#define F_IBT   1024     // 1296
#define F_IO    2320     // 256
#define F_IV    2576     // 5184
#define F_BVT   7760     // 1152
#define F_SX    16384    // 8192
#define F_SWQ   24576    // 1152 (contiguous with SWK/SWV)
#define F_SWK   25728
#define F_SWV   26880
#define F_SWO   28032
#define F_SCTX  32768    // 8192
#define B_R1    1048576ULL                      // fp32 region: Wvm early, ctx (9437184 f) later
#define B_WB    (B_R1 + 37748736ULL)            // 4 bf16 weight buffers
#define B_XB    (B_WB + 4ULL*2654208ULL)        // x_b / ctx_b bf16
#define B_QB    (B_XB + 18874368ULL)            // 25165824 B each (qkv now 18.9MB used)
#define B_KB    (B_QB + 25165824ULL)
#define B_VB    (B_KB + 25165824ULL)
#define B_VT    (B_VB + 25165824ULL)
#define WSLOT   1327104ULL

__device__ __forceinline__ unsigned bf16rne(float f) {
    unsigned u = __builtin_bit_cast(unsigned, f);
    return (u + 0x7fffu + ((u >> 16) & 1u)) >> 16;
}
__device__ __forceinline__ unsigned cvtpk(float lo, float hi) {
    unsigned r;
    asm("v_cvt_pk_bf16_f32 %0, %1, %2" : "=v"(r) : "v"(lo), "v"(hi));
    return r;
}
__device__ __forceinline__ short8 mk8(unsigned a, unsigned b, unsigned c, unsigned d) {
    union { unsigned u[4]; short8 s; } t;
    t.u[0] = a; t.u[1] = b; t.u[2] = c; t.u[3] = d;
    return t.s;
}
__device__ __forceinline__ void async_ld16(void* lds, const void* g) {
    __builtin_amdgcn_global_load_lds((const __attribute__((address_space(1))) unsigned*)g,
                                     (__attribute__((address_space(3))) unsigned*)lds, 16, 0, 0);
}

// ---------------- small-matrix inversion via order-3 Newton-Schulz, 3 steps ----------------
// residual E^2 -> cubed each step -> ~4e-26 after 3 steps: fp32-exact inverse.
__global__ __launch_bounds__(128) void invert_kernel(const float* __restrict__ A32, const float* __restrict__ B36,
                                                     const float* __restrict__ O16, const float* __restrict__ V72,
                                                     float* __restrict__ ws)
{
    __shared__ float As[80*76], Xs[80*76], Ys[80*76], Ps[80*76], Wt[80*76];
    int which = blockIdx.x;
    int n; const float* src;
    if (which == 0)      { n = 32; src = A32; }
    else if (which == 1) { n = 36; src = B36; }
    else if (which == 2) { n = 16; src = O16; }
    else                 { n = 72; src = V72; }
    int tid = threadIdx.x;
    int nq = n >> 2;
    for (int idx = tid; idx < n*n; idx += 128) {
        int i = idx / n, j = idx % n;
        float a = src[idx];
        As[i*76 + j] = a;
        Xs[i*76 + j] = (i == j ? 2.0f : 0.0f) - a;
    }
    __syncthreads();
    int ty = tid >> 3, qq = tid & 7;     // 16 row-groups x 8 quad-lanes

#define NSGEMM(DST, SA, SB) { \
    f32x4 c00={0,0,0,0},c01={0,0,0,0},c02={0,0,0,0}, \
          c10={0,0,0,0},c11={0,0,0,0},c12={0,0,0,0}, \
          c20={0,0,0,0},c21={0,0,0,0},c22={0,0,0,0}, \
          c30={0,0,0,0},c31={0,0,0,0},c32={0,0,0,0}, \
          c40={0,0,0,0},c41={0,0,0,0},c42={0,0,0,0}; \
    _Pragma("unroll 2") \
    for (int k = 0; k < n; ++k) { \
        const float* sb = &SB[k*76]; \
        f32x4 b0 = *(const f32x4*)(sb + 4*qq); \
        f32x4 b1 = *(const f32x4*)(sb + 4*qq + 32); \
        f32x4 b2 = *(const f32x4*)(sb + 4*qq + 64); \
        float a0 = SA[ty*76 + k]; \
        float a1 = SA[(ty+16)*76 + k]; \
        float a2 = SA[(ty+32)*76 + k]; \
        float a3 = SA[(ty+48)*76 + k]; \
        float a4 = SA[(ty+64)*76 + k]; \
        c00 += a0*b0; c01 += a0*b1; c02 += a0*b2; \
        c10 += a1*b0; c11 += a1*b1; c12 += a1*b2; \
        c20 += a2*b0; c21 += a2*b1; c22 += a2*b2; \
        c30 += a3*b0; c31 += a3*b1; c32 += a3*b2; \
        c40 += a4*b0; c41 += a4*b1; c42 += a4*b2; \
    } \
    { \
        f32x4 cc[5][3] = {{c00,c01,c02},{c10,c11,c12},{c20,c21,c22},{c30,c31,c32},{c40,c41,c42}}; \
        _Pragma("unroll") \
        for (int m = 0; m < 5; ++m) { \
            int i = ty + 16*m; \
            if (i < n) { \
                _Pragma("unroll") \
                for (int c = 0; c < 3; ++c) { \
                    int q = qq + 8*c; \
                    if (q < nq) *(f32x4*)&DST[i*76 + 4*q] = cc[m][c]; \
                } \
            } \
        } \
    } \
}
#define NSELEM(P_, Y_) { \
    for (int idx = tid; idx < n*n; idx += 128) { \
        int i = idx / n, j = idx % n; \
        P_[i*76 + j] = P_[i*76 + j] - 3.0f*Y_[i*76 + j] + (i == j ? 3.0f : 0.0f); \
    } \
}
    float* Xc = Xs;
    float* Xn = Wt;
    for (int it = 0; it < 3; ++it) {
        NSGEMM(Ys, As, Xc); __syncthreads();
        NSGEMM(Ps, Ys, Ys); __syncthreads();
        NSELEM(Ps, Ys);     __syncthreads();
        NSGEMM(Xn, Xc, Ps); __syncthreads();
        float* t = Xc; Xc = Xn; Xn = t;
    }
#undef NSGEMM
#undef NSELEM
    if (which == 0) {       // store transposed inverse: ws[l*32+p] = inv[p][l]
        for (int idx = tid; idx < 32*32; idx += 128) { int l = idx/32, pp = idx%32; ws[F_IAT + idx] = Xc[pp*76 + l]; }
    } else if (which == 1) {
        for (int idx = tid; idx < 36*36; idx += 128) { int r = idx/36, qx = idx%36; ws[F_IBT + idx] = Xc[qx*76 + r]; }
    } else if (which == 2) {
        for (int idx = tid; idx < 16*16; idx += 128) { int i = idx/16, j = idx%16; ws[F_IO + idx] = Xc[i*76 + j]; }
    } else {
        for (int idx = tid; idx < 72*72; idx += 128) { int i = idx/72, j = idx%72; ws[F_IV + idx] = Xc[i*76 + j]; }
    }
}

// ---------------- activation kron + fused 8-bit quant ----------------
__global__ __launch_bounds__(256) void kron_act_q(const float* __restrict__ src, unsigned short* __restrict__ dst,
                                                  float* __restrict__ scl,
                                                  const float* __restrict__ P, const float* __restrict__ Q,
                                                  const float* __restrict__ diag)
{
    __shared__ float Xs[LL*RR], T1[LL*RR], Ps[LL*LL], Qs[RR*RR], Ys[LL*RR], red[256];
    int row = blockIdx.x;
    int tid = threadIdx.x;
    const float* sr = src + (size_t)row*DD;
    for (int i = tid; i < LL*LL; i += 256) Ps[i] = P[i];
    for (int i = tid; i < RR*RR; i += 256) Qs[i] = Q[i];
    for (int i = tid; i < DD; i += 256) Xs[i] = sr[i]*diag[i];
    __syncthreads();
    for (int s = tid; s < 288; s += 256) {
        int p = s / 9, r4 = (s % 9)*4;
        f32x4 acc = {0.f,0.f,0.f,0.f};
        #pragma unroll 8
        for (int l = 0; l < LL; ++l) {
            float a = Ps[l*LL + p];
            f32x4 x = *(const f32x4*)&Xs[l*RR + r4];
            acc += a*x;
        }
        *(f32x4*)&T1[p*RR + r4] = acc;
    }
    __syncthreads();
    float lmax = 0.f;
    for (int s = tid; s < 288; s += 256) {
        int p = s / 9, q4 = (s % 9)*4;
        f32x4 acc = {0.f,0.f,0.f,0.f};
        #pragma unroll 9
        for (int r = 0; r < RR; ++r) {
            float t = T1[p*RR + r];
            f32x4 qv = *(const f32x4*)&Qs[r*RR + q4];
            acc += t*qv;
        }
        *(f32x4*)&Ys[p*RR + q4] = acc;
        lmax = fmaxf(lmax, fmaxf(fmaxf(fabsf(acc[0]), fabsf(acc[1])), fmaxf(fabsf(acc[2]), fabsf(acc[3]))));
    }
    red[tid] = lmax; __syncthreads();
    for (int s = 128; s > 0; s >>= 1) { if (tid < s) red[tid] = fmaxf(red[tid], red[tid+s]); __syncthreads(); }
    float scale = fmaxf(red[0]/127.f, 1e-8f);
    float rs = 1.f/scale;
    if (tid == 0) scl[row] = scale;
    for (int s = tid; s < 288; s += 256) {
        int i4 = s*4;
        f32x4 y = *(const f32x4*)&Ys[i4];
        ushort4v o;
        #pragma unroll
        for (int c = 0; c < 4; ++c) {
            float v = rintf(y[c]*rs);
            v = fminf(fmaxf(v, -128.f), 127.f);
            o[c] = (unsigned short)bf16rne(v);
        }
        *(ushort4v*)&dst[(size_t)row*DD + i4] = o;
    }
}

// ---------------- weight kron + fused 4-bit quant ----------------
__global__ __launch_bounds__(256) void kron_w_q(const float* __restrict__ src, unsigned short* __restrict__ dst,
                                                float* __restrict__ scl,
                                                const float* __restrict__ P, const float* __restrict__ Q,
                                                const float* __restrict__ diag)
{
    __shared__ float Xs[LL*RR], T1[LL*RR], Ps[LL*LL], Qs[RR*RR], Ys[LL*RR], red[256];
    int row = blockIdx.x;
    int tid = threadIdx.x;
    const float* sr = src + (size_t)row*DD;
    for (int i = tid; i < LL*LL; i += 256) Ps[i] = P[i];
    for (int i = tid; i < RR*RR; i += 256) Qs[i] = Q[i];
    for (int i = tid; i < DD; i += 256) Xs[i] = sr[i]*(1.0f/diag[i]);
    __syncthreads();
    for (int s = tid; s < 288; s += 256) {
        int p = s / 9, r4 = (s % 9)*4;
        f32x4 acc = {0.f,0.f,0.f,0.f};
        #pragma unroll 8
        for (int l = 0; l < LL; ++l) {
            float a = Ps[l*LL + p];
            f32x4 x = *(const f32x4*)&Xs[l*RR + r4];
            acc += a*x;
        }
        *(f32x4*)&T1[p*RR + r4] = acc;
    }
    __syncthreads();
    float lmax = 0.f;
    for (int s = tid; s < 288; s += 256) {
        int p = s / 9, q4 = (s % 9)*4;
        f32x4 acc = {0.f,0.f,0.f,0.f};
        #pragma unroll 9
        for (int r = 0; r < RR; ++r) {
            float t = T1[p*RR + r];
            f32x4 qv = *(const f32x4*)&Qs[r*RR + q4];
            acc += t*qv;
        }
        *(f32x4*)&Ys[p*RR + q4] = acc;
        lmax = fmaxf(lmax, fmaxf(fmaxf(fabsf(acc[0]), fabsf(acc[1])), fmaxf(fabsf(acc[2]), fabsf(acc[3]))));
    }
    red[tid] = lmax; __syncthreads();
    for (int s = 128; s > 0; s >>= 1) { if (tid < s) red[tid] = fmaxf(red[tid], red[tid+s]); __syncthreads(); }
    float scale = fmaxf(red[0]/7.f, 1e-8f);
    float rs = 1.f/scale;
    if (tid == 0) scl[row] = scale;
    for (int s = tid; s < 288; s += 256) {
        int i4 = s*4;
        f32x4 y = *(const f32x4*)&Ys[i4];
        ushort4v o;
        #pragma unroll
        for (int c = 0; c < 4; ++c) {
            float v = rintf(y[c]*rs);
            v = fminf(fmaxf(v, -8.f), 7.f);
            o[c] = (unsigned short)bf16rne(v);
        }
        *(ushort4v*)&dst[(size_t)row*DD + i4] = o;
    }
}

// ---------------- plain kron (fp32 out) for Wv pre-fold ----------------
__global__ __launch_bounds__(256) void kron_rows(const float* __restrict__ src, float* __restrict__ dst,
                                                 const float* __restrict__ P, const float* __restrict__ Q,
                                                 const float* __restrict__ diag)
{
    __shared__ float Xs[LL*RR], T1[LL*RR], Ps[LL*LL], Qs[RR*RR];
    int row = blockIdx.x;
    int tid = threadIdx.x;
    const float* sr = src + (size_t)row*DD;
    for (int i = tid; i < LL*LL; i += 256) Ps[i] = P[i];
    for (int i = tid; i < RR*RR; i += 256) Qs[i] = Q[i];
    for (int i = tid; i < DD; i += 256) Xs[i] = sr[i]*(1.0f/diag[i]);
    __syncthreads();
    for (int s = tid; s < 288; s += 256) {
        int p = s / 9, r4 = (s % 9)*4;
        f32x4 acc = {0.f,0.f,0.f,0.f};
        #pragma unroll 8
        for (int l = 0; l < LL; ++l) {
            float a = Ps[l*LL + p];
            f32x4 x = *(const f32x4*)&Xs[l*RR + r4];
            acc += a*x;
        }
        *(f32x4*)&T1[p*RR + r4] = acc;
    }
    __syncthreads();
    for (int s = tid; s < 288; s += 256) {
        int p = s / 9, q4 = (s % 9)*4;
        f32x4 acc = {0.f,0.f,0.f,0.f};
        #pragma unroll 9
        for (int r = 0; r < RR; ++r) {
            float t = T1[p*RR + r];
            f32x4 qv = *(const f32x4*)&Qs[r*RR + q4];
            acc += t*qv;
        }
        *(f32x4*)&dst[(size_t)row*DD + p*RR + q4] = acc;
    }
}

// ---------------- Wv out-channel fold + fused 4-bit quant ----------------
__global__ __launch_bounds__(256) void wv_fold_q(const float* __restrict__ tmp, const float* __restrict__ vc,
                                                 const float* __restrict__ bv, unsigned short* __restrict__ dst,
                                                 float* __restrict__ scl, float* __restrict__ bvt)
{
    int he = blockIdx.x;
    int h = he / HD, e = he % HD;
    __shared__ float vcol[HD], Ys[DD], red[256];
    int tid = threadIdx.x;
    if (tid < HD) vcol[tid] = vc[tid*HD + e];
    __syncthreads();
    const float* base = tmp + (size_t)h*HD*DD;
    float lmax = 0.f;
    for (int i = tid; i < DD; i += 256) {
        float acc = 0.f;
        #pragma unroll 8
        for (int d = 0; d < HD; ++d) acc += base[(size_t)d*DD + i]*vcol[d];
        Ys[i] = acc;
        lmax = fmaxf(lmax, fabsf(acc));
    }
    red[tid] = lmax; __syncthreads();
    for (int s = 128; s > 0; s >>= 1) { if (tid < s) red[tid] = fmaxf(red[tid], red[tid+s]); __syncthreads(); }
    float scale = fmaxf(red[0]/7.f, 1e-8f);
    float rs = 1.f/scale;
    if (tid == 0) {
        scl[he] = scale;
        float acc = 0.f;
        for (int d = 0; d < HD; ++d) acc += bv[h*HD + d]*vcol[d];
        bvt[he] = acc;
    }
    for (int i = tid; i < DD; i += 256) {
        float v = rintf(Ys[i]*rs);
        v = fminf(fmaxf(v, -8.f), 7.f);
        dst[(size_t)he*DD + i] = (unsigned short)bf16rne(v);
    }
}

// ---------------- Wo transform + fused 4-bit quant ----------------
__global__ __launch_bounds__(256) void wo_trans_q(const float* __restrict__ Wo, const float* __restrict__ iO,
                                                  const float* __restrict__ iV, unsigned short* __restrict__ dst,
                                                  float* __restrict__ scl)
{
    __shared__ float M[HH*HD], T1[HH*HD], iOs[HH*HH], iVs[HD*HD], Ys[DD], red[256];
    int row = blockIdx.x, tid = threadIdx.x;
    for (int i = tid; i < DD; i += 256) M[i] = Wo[(size_t)row*DD + i];
    for (int i = tid; i < HH*HH; i += 256) iOs[i] = iO[i];
    for (int i = tid; i < HD*HD; i += 256) iVs[i] = iV[i];
    __syncthreads();
    for (int i = tid; i < DD; i += 256) {
        int h = i / HD, d = i % HD;
        float a = 0.f;
        #pragma unroll
        for (int g = 0; g < HH; ++g) a += iOs[h*HH + g]*M[g*HD + d];
        T1[i] = a;
    }
    __syncthreads();
    float lmax = 0.f;
    for (int i = tid; i < DD; i += 256) {
        int h = i / HD, e = i % HD;
        float a = 0.f;
        #pragma unroll 8
        for (int d = 0; d < HD; ++d) a += T1[h*HD + d]*iVs[e*HD + d];
        Ys[i] = a;
        lmax = fmaxf(lmax, fabsf(a));
    }
    red[tid] = lmax; __syncthreads();
    for (int s = 128; s > 0; s >>= 1) { if (tid < s) red[tid] = fmaxf(red[tid], red[tid+s]); __syncthreads(); }
    float scale = fmaxf(red[0]/7.f, 1e-8f);
    float rs = 1.f/scale;
    if (tid == 0) scl[row] = scale;
    for (int i = tid; i < DD; i += 256) {
        float v = rintf(Ys[i]*rs);
        v = fminf(fmaxf(v, -8.f), 7.f);
        dst[(size_t)row*DD + i] = (unsigned short)bf16rne(v);
    }
}

// ---------------- MFMA GEMM core ----------------
__device__ __forceinline__ void gemm_body(const unsigned short* __restrict__ Xb, const unsigned short* __restrict__ Wb,
                                          unsigned short* As, unsigned short* Bs, f32x4 (&acc)[4][4],
                                          int wr, int wc, int lr, int lg)
{
    for (int k0 = 0; k0 < DD; k0 += 32) {
        int tid = threadIdx.x;
        #pragma unroll
        for (int j = 0; j < 2; ++j) {
            int idx = tid + j*256;
            int row = idx >> 2, pp = idx & 3;
            int s = pp ^ ((row >> 1) & 3);
            async_ld16(&As[idx*8], Xb + (size_t)row*DD + k0 + s*8);
            async_ld16(&Bs[idx*8], Wb + (size_t)row*DD + k0 + s*8);
        }
        __syncthreads();
        short8 a[4], bfr[4];
        #pragma unroll
        for (int fr = 0; fr < 4; ++fr) {
            int row = wr*64 + fr*16 + lr;
            a[fr] = *(const short8*)(&As[row*32 + (lg ^ ((row>>1)&3))*8]);
        }
        #pragma unroll
        for (int fc = 0; fc < 4; ++fc) {
            int row = wc*64 + fc*16 + lr;
            bfr[fc] = *(const short8*)(&Bs[row*32 + (lg ^ ((row>>1)&3))*8]);
        }
        #pragma unroll
        for (int fr = 0; fr < 4; ++fr)
            #pragma unroll
            for (int fc = 0; fc < 4; ++fc)
                acc[fr][fc] = __builtin_amdgcn_mfma_f32_16x16x32_bf16(a[fr], bfr[fc], acc[fr][fc], 0, 0, 0);
        __syncthreads();
    }
}

// ---------------- merged q/k/v projection GEMM, token-major bf16 out, XCD-swizzled ----------------
// grid: 1728 = 8 XCD chunks x 216; out[tok][1152] bf16 via LDS repack (coalesced 256B rows)
__global__ __launch_bounds__(256) void gemm_qkv(const unsigned short* __restrict__ X,
                                                const unsigned short* __restrict__ Wq_b,
                                                const unsigned short* __restrict__ Wk_b,
                                                const unsigned short* __restrict__ Wv_b,
                                                const float* __restrict__ sx, const float* __restrict__ ws_all,
                                                const float* __restrict__ bq, const float* __restrict__ bk,
                                                const float* __restrict__ bvt,
                                                unsigned short* __restrict__ qb, unsigned short* __restrict__ kb,
                                                unsigned short* __restrict__ vb)
{
    __shared__ unsigned short smem[8192];   // As | Bs during K-loop; 64x128 bf16 tile for repack
    unsigned short* As = smem;
    unsigned short* Bs = smem + 4096;
    int lin = blockIdx.x;
    int nl = (lin & 7)*216 + (lin >> 3);    // XCD-contiguous chunks (1728 % 8 == 0: bijective)
    int z = nl / 576;
    int rem = nl - z*576;
    int bm = rem / 9, bn = rem - bm*9;
    const unsigned short* W = (z == 0) ? Wq_b : (z == 1) ? Wk_b : Wv_b;
    const float* sw_ = ws_all + (size_t)z*1152;
    const float* bias = (z == 0) ? bq : (z == 1) ? bk : bvt;
    unsigned short* outQ = (z == 0) ? qb : (z == 1) ? kb : vb;
    int tid = threadIdx.x;
    int wave = tid >> 6, lane = tid & 63;
    int wr = wave >> 1, wc = wave & 1;
    int lr = lane & 15, lg = lane >> 4;
    f32x4 acc[4][4];
    #pragma unroll
    for (int i = 0; i < 4; ++i)
        #pragma unroll
        for (int j = 0; j < 4; ++j)
            #pragma unroll
            for (int e = 0; e < 4; ++e) acc[i][j][e] = 0.f;
    gemm_body(X + (size_t)bm*128*DD, W + (size_t)bn*128*DD, As, Bs, acc, wr, wc, lr, lg);
    // epilogue: scale+bias -> bf16, LDS repack (2 half-tiles of 64 rows), coalesced store
    float swn[4], bnv[4];
    #pragma unroll
    for (int fc = 0; fc < 4; ++fc) {
        int n = bn*128 + wc*64 + fc*16 + lr;
        swn[fc] = sw_[n]; bnv[fc] = bias[n];
    }
    #pragma unroll
    for (int c = 0; c < 2; ++c) {
        __syncthreads();
        if (wr == c) {
            #pragma unroll
            for (int fr = 0; fr < 4; ++fr) {
                #pragma unroll
                for (int j = 0; j < 4; ++j) {
                    int rloc = fr*16 + lg*4 + j;
                    float sxm = sx[bm*128 + c*64 + rloc];
                    #pragma unroll
                    for (int fc = 0; fc < 4; ++fc) {
                        int cloc = wc*64 + fc*16 + lr;
                        float v = acc[fr][fc][j]*sxm*swn[fc] + bnv[fc];
                        smem[rloc*128 + cloc] = (unsigned short)bf16rne(v);
                    }
                }
            }
        }
        __syncthreads();
        #pragma unroll
        for (int it = 0; it < 4; ++it) {
            int idx = tid + it*256;          // 0..1023: 64 rows x 16 segs of 16B
            int row = idx >> 4, seg = idx & 15;
            size_t g = ((size_t)(bm*128 + c*64 + row))*DD + bn*128 + seg*8;
            *(short8*)(&outQ[g]) = *(const short8*)(&smem[row*128 + seg*8]);
        }
    }
}

// ---------------- output projection GEMM (fp32 out), XCD-swizzled ----------------
__global__ __launch_bounds__(256) void gemm_out(const unsigned short* __restrict__ X, const unsigned short* __restrict__ W,
                                                const float* __restrict__ sx, const float* __restrict__ sw_,
                                                const float* __restrict__ bias, float* __restrict__ outF)
{
    __shared__ unsigned short As[128*32];
    __shared__ unsigned short Bs[128*32];
    int lin = blockIdx.x;
    int nl = (lin & 7)*72 + (lin >> 3);     // 576 % 8 == 0
    int bm = nl / 9, bn = nl - bm*9;
    int tid = threadIdx.x;
    int wave = tid >> 6, lane = tid & 63;
    int wr = wave >> 1, wc = wave & 1;
    int lr = lane & 15, lg = lane >> 4;
    f32x4 acc[4][4];
    #pragma unroll
    for (int i = 0; i < 4; ++i)
        #pragma unroll
        for (int j = 0; j < 4; ++j)
            #pragma unroll
            for (int e = 0; e < 4; ++e) acc[i][j][e] = 0.f;
    gemm_body(X + (size_t)bm*128*DD, W + (size_t)bn*128*DD, As, Bs, acc, wr, wc, lr, lg);
    #pragma unroll
    for (int fc = 0; fc < 4; ++fc) {
        int n = bn*128 + wc*64 + fc*16 + lr;
        float swn = sw_[n], bnv = bias[n];
        #pragma unroll
        for (int fr = 0; fr < 4; ++fr) {
            #pragma unroll
            for (int j = 0; j < 4; ++j) {
                int mrow = bm*128 + wr*64 + fr*16 + lg*4 + j;
                outF[(size_t)mrow*DD + n] = acc[fr][fc][j]*sx[mrow]*swn + bnv;
            }
        }
    }
}

// ---------------- transpose V token-major [tok][1152] -> vT (B,H,96,S) bf16 (pad d>=72 zero) ----------------
__global__ __launch_bounds__(256) void transpose_v(const unsigned short* __restrict__ v, unsigned short* __restrict__ vT)
{
    __shared__ unsigned short t[64][100];
    int head = blockIdx.x >> 4, st = blockIdx.x & 15;
    int b = head >> 4, h = head & 15;
    int tid = threadIdx.x;
    const unsigned short* src = v + ((size_t)(b*SS + st*64))*DD + h*HD;
    for (int idx = tid; idx < 64*PD; idx += 256) {
        int i = idx / PD, d = idx % PD;
        t[i][d] = (d < HD) ? src[(size_t)i*DD + d] : (unsigned short)0;
    }
    __syncthreads();
    unsigned short* dst = vT + (size_t)head*PD*SS + st*64;
    for (int idx = tid; idx < PD*64; idx += 256) {
        int d = idx >> 6, i = idx & 63;
        dst[(size_t)d*SS + i] = t[i][d];
    }
}

// ---------------- MFMA flash attention, token-major q/k, XCD-swizzled ----------------
__global__ __launch_bounds__(256) void attn_mfma(const unsigned short* __restrict__ q, const unsigned short* __restrict__ k,
                                                 const unsigned short* __restrict__ vT, float* __restrict__ ctx)
{
    __shared__ unsigned short Kl[64*128];
    __shared__ unsigned short Vl[96*64];
    int lin = blockIdx.x;
    int nl = (lin & 7)*128 + (lin >> 3);    // 1024 % 8 == 0: all 8 q-blocks of a head per XCD
    int bh = nl >> 3;
    int qblk = nl & 7;
    int tid = threadIdx.x;
    int wave = tid >> 6, lane = tid & 63;
    int lq = lane & 31, half = lane >> 5;
    int b = bh >> 4, h = bh & 15;
    const unsigned short* qrow = q + ((size_t)(b*SS + qblk*128 + wave*32 + lq))*DD + h*HD;
    const unsigned short* kbb  = k + (size_t)b*SS*DD + h*HD;
    const unsigned short* vtb  = vT + (size_t)bh*PD*SS;
    short8 zero8 = {0,0,0,0,0,0,0,0};
    // Q fragments: k-dim = ks*16 + half*8 + (0..7); valid only < 72
    short8 qf[6];
    #pragma unroll
    for (int ks = 0; ks < 4; ++ks)
        qf[ks] = *(const short8*)(qrow + ks*16 + half*8);
    qf[4] = (half == 0) ? *(const short8*)(qrow + 64) : zero8;
    qf[5] = zero8;
    f32x16 O0, O1, O2;
    #pragma unroll
    for (int r = 0; r < 16; ++r) { O0[r] = 0.f; O1[r] = 0.f; O2[r] = 0.f; }
    float m = -1e30f, l = 0.f;
    for (int t0 = 0; t0 < SS; t0 += 64) {
        __syncthreads();
        // stage K tile: 64 keys x 12 slots (s<9 real, else zero), swizzled
        #pragma unroll
        for (int j = 0; j < 3; ++j) {
            int idx = tid + j*256;
            int row = idx / 12, s = idx % 12;
            int phys = s ^ (row & 7);
            short8 val = zero8;
            if (s < 9) val = *(const short8*)(kbb + (size_t)(t0 + row)*DD + s*8);
            *(short8*)(&Kl[row*128 + phys*8]) = val;
        }
        // stage V^T tile [96 d][8 slots] swizzled
        #pragma unroll
        for (int j = 0; j < 3; ++j) {
            int idx = tid + j*256;
            int d = idx >> 3, p = idx & 7;
            int s = p ^ (d & 7);
            short8 val = *(const short8*)(vtb + (size_t)d*SS + t0 + s*8);
            *(short8*)(&Vl[d*64 + p*8]) = val;
        }
        __syncthreads();
        #pragma unroll
        for (int sub = 0; sub < 2; ++sub) {
            f32x16 sacc;
            #pragma unroll
            for (int r = 0; r < 16; ++r) sacc[r] = 0.f;
            __builtin_amdgcn_s_setprio(1);
            #pragma unroll
            for (int ks = 0; ks < 6; ++ks) {
                int key = sub*32 + lq;
                short8 kf = *(const short8*)(&Kl[key*128 + (((ks*2 + half) ^ (lq & 7)))*8]);
                sacc = __builtin_amdgcn_mfma_f32_32x32x16_bf16(kf, qf[ks], sacc, 0, 0, 0);
            }
            __builtin_amdgcn_s_setprio(0);
            float pa = fmaxf(fmaxf(sacc[0], sacc[1]), fmaxf(sacc[2], sacc[3]));
            float pb = fmaxf(fmaxf(sacc[4], sacc[5]), fmaxf(sacc[6], sacc[7]));
            float pc = fmaxf(fmaxf(sacc[8], sacc[9]), fmaxf(sacc[10], sacc[11]));
            float pd = fmaxf(fmaxf(sacc[12], sacc[13]), fmaxf(sacc[14], sacc[15]));
            float pmax = fmaxf(fmaxf(pa, pb), fmaxf(pc, pd));
            pmax = fmaxf(pmax, __shfl_xor(pmax, 32));
            if (!__all(pmax - m <= 8.0f)) {
                float mn = fmaxf(m, pmax);
                float corr = __expf(m - mn);
                m = mn;
                l *= corr;
                #pragma unroll
                for (int r = 0; r < 16; ++r) {
                    int rowq = (r&3) + 8*(r>>2) + 4*half;
                    float cr = __shfl(corr, rowq);
                    O0[r] *= cr; O1[r] *= cr; O2[r] *= cr;
                }
            }
            float p[16]; float ls = 0.f;
            #pragma unroll
            for (int r = 0; r < 16; ++r) { p[r] = __expf(sacc[r] - m); ls += p[r]; }
            ls += __shfl_xor(ls, 32);
            l += ls;
            unsigned pk[8], sw[8];
            #pragma unroll
            for (int j2 = 0; j2 < 8; ++j2) pk[j2] = cvtpk(p[2*j2], p[2*j2+1]);
            #pragma unroll
            for (int j2 = 0; j2 < 8; ++j2) sw[j2] = __shfl_xor(pk[j2], 32);
            short8 A0 = half ? mk8(sw[2], sw[3], pk[2], pk[3]) : mk8(pk[0], pk[1], sw[0], sw[1]);
            short8 A1 = half ? mk8(sw[6], sw[7], pk[6], pk[7]) : mk8(pk[4], pk[5], sw[4], sw[5]);
            __builtin_amdgcn_s_setprio(1);
            #pragma unroll
            for (int dt = 0; dt < 3; ++dt) {
                int d = dt*32 + lq;
                short8 vf0 = *(const short8*)(&Vl[d*64 + (((sub*4 + half) ^ (d & 7)))*8]);
                short8 vf1 = *(const short8*)(&Vl[d*64 + (((sub*4 + 2 + half) ^ (d & 7)))*8]);
                if (dt == 0) { O0 = __builtin_amdgcn_mfma_f32_32x32x16_bf16(A0, vf0, O0, 0,0,0);
                               O0 = __builtin_amdgcn_mfma_f32_32x32x16_bf16(A1, vf1, O0, 0,0,0); }
                if (dt == 1) { O1 = __builtin_amdgcn_mfma_f32_32x32x16_bf16(A0, vf0, O1, 0,0,0);
                               O1 = __builtin_amdgcn_mfma_f32_32x32x16_bf16(A1, vf1, O1, 0,0,0); }
                if (dt == 2) { O2 = __builtin_amdgcn_mfma_f32_32x32x16_bf16(A0, vf0, O2, 0,0,0);
                               O2 = __builtin_amdgcn_mfma_f32_32x32x16_bf16(A1, vf1, O2, 0,0,0); }
            }
            __builtin_amdgcn_s_setprio(0);
        }
    }
    float linv = 1.f / l;
    #pragma unroll
    for (int r = 0; r < 16; ++r) {
        int rowq = (r&3) + 8*(r>>2) + 4*half;
        float lr2 = __shfl(linv, rowq);
        int s = qblk*128 + wave*32 + rowq;
        size_t base = ((size_t)(b*SS + s))*DD + h*HD;
        ctx[base + lq]      = O0[r]*lr2;
        ctx[base + 32 + lq] = O1[r]*lr2;
        if (lq < 8) ctx[base + 64 + lq] = O2[r]*lr2;
    }
}

// ---------------- head mix + 8-bit quant ----------------
__global__ __launch_bounds__(256) void octx_fq_q(const float* __restrict__ ctx, const float* __restrict__ o_mat,
                                                 unsigned short* __restrict__ out, float* __restrict__ scl)
{
    __shared__ float ct[DD], Ys[DD], om[HH*HH], red[256];
    int t = blockIdx.x, tid = threadIdx.x;
    for (int i = tid; i < DD; i += 256) ct[i] = ctx[(size_t)t*DD + i];
    for (int i = tid; i < HH*HH; i += 256) om[i] = o_mat[i];
    __syncthreads();
    float lmax = 0.f;
    for (int s = tid; s < 288; s += 256) {
        int h = s / 18, d4 = (s % 18)*4;
        f32x4 acc = {0.f,0.f,0.f,0.f};
        #pragma unroll
        for (int g = 0; g < HH; ++g) {
            float o = om[g*HH + h];
            f32x4 c = *(const f32x4*)&ct[g*HD + d4];
            acc += o*c;
        }
        *(f32x4*)&Ys[h*HD + d4] = acc;
        lmax = fmaxf(lmax, fmaxf(fmaxf(fabsf(acc[0]), fabsf(acc[1])), fmaxf(fabsf(acc[2]), fabsf(acc[3]))));
    }
    red[tid] = lmax; __syncthreads();
    for (int s = 128; s > 0; s >>= 1) { if (tid < s) red[tid] = fmaxf(red[tid], red[tid+s]); __syncthreads(); }
    float scale = fmaxf(red[0]/127.f, 1e-8f);
    float rs = 1.f/scale;
    if (tid == 0) scl[t] = scale;
    for (int s = tid; s < 288; s += 256) {
        int i4 = s*4;
        f32x4 y = *(const f32x4*)&Ys[i4];
        ushort4v o;
        #pragma unroll
        for (int c = 0; c < 4; ++c) {
            float v = rintf(y[c]*rs);
            v = fminf(fmaxf(v, -128.f), 127.f);
            o[c] = (unsigned short)bf16rne(v);
        }
        *(ushort4v*)&out[(size_t)t*DD + i4] = o;
    }
}

extern "C" void kernel_launch(void* const* d_in, const int* in_sizes, int n_in,
                              void* d_out, int out_size, void* d_ws, size_t ws_size,
                              hipStream_t stream)
{
    const float* hidden = (const float*)d_in[0];
    const float* Wq = (const float*)d_in[1];  const float* bq = (const float*)d_in[2];
    const float* Wk = (const float*)d_in[3];  const float* bk = (const float*)d_in[4];
    const float* Wv = (const float*)d_in[5];  const float* bv = (const float*)d_in[6];
    const float* Wo = (const float*)d_in[7];  const float* bo = (const float*)d_in[8];
    const float* lnA = (const float*)d_in[9];
    const float* lnB = (const float*)d_in[10];
    const float* ln_diag = (const float*)d_in[11];
    const float* vc = (const float*)d_in[12];
    const float* o_mat = (const float*)d_in[13];
    float* ws = (float*)d_ws;
    float* out = (float*)d_out;
    char* wsb = (char*)d_ws;

    float* iAT  = ws + F_IAT;
    float* iBT  = ws + F_IBT;
    float* iO   = ws + F_IO;
    float* iV   = ws + F_IV;
    float* bvt  = ws + F_BVT;
    float* s_x  = ws + F_SX;
    float* s_wq = ws + F_SWQ;   // s_wq/s_wk/s_wv contiguous (ws_all)
    float* s_wk = ws + F_SWK;
    float* s_wv = ws + F_SWV;
    float* s_wo = ws + F_SWO;
    float* s_ct = ws + F_SCTX;

    float* slot = (float*)(wsb + B_R1);
    float* Wvm  = slot + 2*WSLOT;
    float* ctxf = slot;

    unsigned short* Wq_b = (unsigned short*)(wsb + B_WB);
    unsigned short* Wk_b = Wq_b + WSLOT;
    unsigned short* Wv_b = Wq_b + 2*WSLOT;
    unsigned short* Wo_b = Wq_b + 3*WSLOT;
    unsigned short* x_b  = (unsigned short*)(wsb + B_XB);
    unsigned short* ctx_b = x_b;
    unsigned short* qb = (unsigned short*)(wsb + B_QB);
    unsigned short* kb = (unsigned short*)(wsb + B_KB);
    unsigned short* vb = (unsigned short*)(wsb + B_VB);
    unsigned short* vT = (unsigned short*)(wsb + B_VT);

    // 1. small inversions (order-3 Newton-Schulz x3: fp32-exact)
    invert_kernel<<<4, 128, 0, stream>>>(lnA, lnB, o_mat, vc, ws);
    // 2. activation kron + 8-bit quant
    kron_act_q<<<NTOK, 256, 0, stream>>>(hidden, x_b, s_x, lnA, lnB, ln_diag);
    // 3. weight transforms (+fused 4-bit quant)
    kron_w_q<<<DD, 256, 0, stream>>>(Wq, Wq_b, s_wq, iAT, iBT, ln_diag);
    kron_w_q<<<DD, 256, 0, stream>>>(Wk, Wk_b, s_wk, iAT, iBT, ln_diag);
    kron_rows<<<DD, 256, 0, stream>>>(Wv, Wvm, iAT, iBT, ln_diag);
    wv_fold_q<<<DD, 256, 0, stream>>>(Wvm, vc, bv, Wv_b, s_wv, bvt);
    wo_trans_q<<<DD, 256, 0, stream>>>(Wo, iO, iV, Wo_b, s_wo);
    // 4. merged q/k/v projections -> token-major bf16 (XCD-swizzled, LDS-repacked writes)
    gemm_qkv<<<dim3(1728), 256, 0, stream>>>(x_b, Wq_b, Wk_b, Wv_b, s_x, s_wq, bq, bk, bvt, qb, kb, vb);
    // 5. V transpose (token-major -> (B,H,96,S), pad zeroed)
    transpose_v<<<BB*HH*16, 256, 0, stream>>>(vb, vT);
    // 6. flash attention (XCD-swizzled)
    attn_mfma<<<dim3(1024), 256, 0, stream>>>(qb, kb, vT, ctxf);
    // 7. head-mix + 8-bit quant
    octx_fq_q<<<NTOK, 256, 0, stream>>>(ctxf, o_mat, ctx_b, s_ct);
    // 8. output projection (fp32 out, XCD-swizzled)
    gemm_out<<<dim3(576), 256, 0, stream>>>(ctx_b, Wo_b, s_ct, s_wo, bo, out);
}

// Round 8
// 597.144 us; speedup vs baseline: 1.0391x; 1.0391x over previous
//
#include <hip/hip_runtime.h>
#include <hip/hip_bf16.h>

// Problem dims
#define BB 8
#define SS 1024
#define DD 1152
#define HH 16
#define HD 72
#define PD 96          // padded head dim inside attention MFMA only
#define LL 32
#define RR 36
#define NTOK (BB*SS)   // 8192

typedef __attribute__((ext_vector_type(8)))  short short8;
typedef __attribute__((ext_vector_type(4)))  float f32x4;
typedef __attribute__((ext_vector_type(16))) float f32x16;
typedef __attribute__((ext_vector_type(4)))  unsigned short ushort4v;

// ---------- workspace layout ----------
#define F_IAT   0        // 1024
#define F_IBT   1024     // 1296
#define F_IO    2320     // 256
#define F_IV    2576     // 5184
#define F_BVT   7760     // 1152
#define F_SX    16384    // 8192
#define F_SWQ   24576    // 1152 (contiguous with SWK/SWV)
#define F_SWK   25728
#define F_SWV   26880
#define F_SWO   28032
#define F_SCTX  32768    // 8192
#define B_R1    1048576ULL                      // fp32 region: Wvm early, ctx (9437184 f) later
#define B_WB    (B_R1 + 37748736ULL)            // 4 bf16 weight buffers
#define B_XB    (B_WB + 4ULL*2654208ULL)        // x_b / ctx_b bf16
#define B_QB    (B_XB + 18874368ULL)            // 25165824 B each
#define B_KB    (B_QB + 25165824ULL)
#define B_VB    (B_KB + 25165824ULL)
#define B_VT    (B_VB + 25165824ULL)
#define WSLOT   1327104ULL

__device__ __forceinline__ unsigned bf16rne(float f) {
    unsigned u = __builtin_bit_cast(unsigned, f);
    return (u + 0x7fffu + ((u >> 16) & 1u)) >> 16;
}
__device__ __forceinline__ unsigned cvtpk(float lo, float hi) {
    unsigned r;
    asm("v_cvt_pk_bf16_f32 %0, %1, %2" : "=v"(r) : "v"(lo), "v"(hi));
    return r;
}
__device__ __forceinline__ short8 mk8(unsigned a, unsigned b, unsigned c, unsigned d) {
    union { unsigned u[4]; short8 s; } t;
    t.u[0] = a; t.u[1] = b; t.u[2] = c; t.u[3] = d;
    return t.s;
}
__device__ __forceinline__ void async_ld16(void* lds, const void* g) {
    __builtin_amdgcn_global_load_lds((const __attribute__((address_space(1))) unsigned*)g,
                                     (__attribute__((address_space(3))) unsigned*)lds, 16, 0, 0);
}

// ---------------- small-matrix inversion via order-3 Newton-Schulz, 3 steps ----------------
__global__ __launch_bounds__(128) void invert_kernel(const float* __restrict__ A32, const float* __restrict__ B36,
                                                     const float* __restrict__ O16, const float* __restrict__ V72,
                                                     float* __restrict__ ws)
{
    __shared__ float As[80*76], Xs[80*76], Ys[80*76], Ps[80*76], Wt[80*76];
    int which = blockIdx.x;
    int n; const float* src;
    if (which == 0)      { n = 32; src = A32; }
    else if (which == 1) { n = 36; src = B36; }
    else if (which == 2) { n = 16; src = O16; }
    else                 { n = 72; src = V72; }
    int tid = threadIdx.x;
    int nq = n >> 2;
    for (int idx = tid; idx < n*n; idx += 128) {
        int i = idx / n, j = idx % n;
        float a = src[idx];
        As[i*76 + j] = a;
        Xs[i*76 + j] = (i == j ? 2.0f : 0.0f) - a;
    }
    __syncthreads();
    int ty = tid >> 3, qq = tid & 7;

#define NSGEMM(DST, SA, SB) { \
    f32x4 c00={0,0,0,0},c01={0,0,0,0},c02={0,0,0,0}, \
          c10={0,0,0,0},c11={0,0,0,0},c12={0,0,0,0}, \
          c20={0,0,0,0},c21={0,0,0,0},c22={0,0,0,0}, \
          c30={0,0,0,0},c31={0,0,0,0},c32={0,0,0,0}, \
          c40={0,0,0,0},c41={0,0,0,0},c42={0,0,0,0}; \
    _Pragma("unroll 2") \
    for (int k = 0; k < n; ++k) { \
        const float* sb = &SB[k*76]; \
        f32x4 b0 = *(const f32x4*)(sb + 4*qq); \
        f32x4 b1 = *(const f32x4*)(sb + 4*qq + 32); \
        f32x4 b2 = *(const f32x4*)(sb + 4*qq + 64); \
        float a0 = SA[ty*76 + k]; \
        float a1 = SA[(ty+16)*76 + k]; \
        float a2 = SA[(ty+32)*76 + k]; \
        float a3 = SA[(ty+48)*76 + k]; \
        float a4 = SA[(ty+64)*76 + k]; \
        c00 += a0*b0; c01 += a0*b1; c02 += a0*b2; \
        c10 += a1*b0; c11 += a1*b1; c12 += a1*b2; \
        c20 += a2*b0; c21 += a2*b1; c22 += a2*b2; \
        c30 += a3*b0; c31 += a3*b1; c32 += a3*b2; \
        c40 += a4*b0; c41 += a4*b1; c42 += a4*b2; \
    } \
    { \
        f32x4 cc[5][3] = {{c00,c01,c02},{c10,c11,c12},{c20,c21,c22},{c30,c31,c32},{c40,c41,c42}}; \
        _Pragma("unroll") \
        for (int m = 0; m < 5; ++m) { \
            int i = ty + 16*m; \
            if (i < n) { \
                _Pragma("unroll") \
                for (int c = 0; c < 3; ++c) { \
                    int q = qq + 8*c; \
                    if (q < nq) *(f32x4*)&DST[i*76 + 4*q] = cc[m][c]; \
                } \
            } \
        } \
    } \
}
#define NSELEM(P_, Y_) { \
    for (int idx = tid; idx < n*n; idx += 128) { \
        int i = idx / n, j = idx % n; \
        P_[i*76 + j] = P_[i*76 + j] - 3.0f*Y_[i*76 + j] + (i == j ? 3.0f : 0.0f); \
    } \
}
    float* Xc = Xs;
    float* Xn = Wt;
    for (int it = 0; it < 3; ++it) {
        NSGEMM(Ys, As, Xc); __syncthreads();
        NSGEMM(Ps, Ys, Ys); __syncthreads();
        NSELEM(Ps, Ys);     __syncthreads();
        NSGEMM(Xn, Xc, Ps); __syncthreads();
        float* t = Xc; Xc = Xn; Xn = t;
    }
#undef NSGEMM
#undef NSELEM
    if (which == 0) {
        for (int idx = tid; idx < 32*32; idx += 128) { int l = idx/32, pp = idx%32; ws[F_IAT + idx] = Xc[pp*76 + l]; }
    } else if (which == 1) {
        for (int idx = tid; idx < 36*36; idx += 128) { int r = idx/36, qx = idx%36; ws[F_IBT + idx] = Xc[qx*76 + r]; }
    } else if (which == 2) {
        for (int idx = tid; idx < 16*16; idx += 128) { int i = idx/16, j = idx%16; ws[F_IO + idx] = Xc[i*76 + j]; }
    } else {
        for (int idx = tid; idx < 72*72; idx += 128) { int i = idx/72, j = idx%72; ws[F_IV + idx] = Xc[i*76 + j]; }
    }
}

// ---------------- activation kron + fused 8-bit quant ----------------
__global__ __launch_bounds__(256) void kron_act_q(const float* __restrict__ src, unsigned short* __restrict__ dst,
                                                  float* __restrict__ scl,
                                                  const float* __restrict__ P, const float* __restrict__ Q,
                                                  const float* __restrict__ diag)
{
    __shared__ float Xs[LL*RR], T1[LL*RR], Ps[LL*LL], Qs[RR*RR], Ys[LL*RR], red[256];
    int row = blockIdx.x;
    int tid = threadIdx.x;
    const float* sr = src + (size_t)row*DD;
    for (int i = tid; i < LL*LL; i += 256) Ps[i] = P[i];
    for (int i = tid; i < RR*RR; i += 256) Qs[i] = Q[i];
    for (int i = tid; i < DD; i += 256) Xs[i] = sr[i]*diag[i];
    __syncthreads();
    for (int s = tid; s < 288; s += 256) {
        int p = s / 9, r4 = (s % 9)*4;
        f32x4 acc = {0.f,0.f,0.f,0.f};
        #pragma unroll 8
        for (int l = 0; l < LL; ++l) {
            float a = Ps[l*LL + p];
            f32x4 x = *(const f32x4*)&Xs[l*RR + r4];
            acc += a*x;
        }
        *(f32x4*)&T1[p*RR + r4] = acc;
    }
    __syncthreads();
    float lmax = 0.f;
    for (int s = tid; s < 288; s += 256) {
        int p = s / 9, q4 = (s % 9)*4;
        f32x4 acc = {0.f,0.f,0.f,0.f};
        #pragma unroll 9
        for (int r = 0; r < RR; ++r) {
            float t = T1[p*RR + r];
            f32x4 qv = *(const f32x4*)&Qs[r*RR + q4];
            acc += t*qv;
        }
        *(f32x4*)&Ys[p*RR + q4] = acc;
        lmax = fmaxf(lmax, fmaxf(fmaxf(fabsf(acc[0]), fabsf(acc[1])), fmaxf(fabsf(acc[2]), fabsf(acc[3]))));
    }
    red[tid] = lmax; __syncthreads();
    for (int s = 128; s > 0; s >>= 1) { if (tid < s) red[tid] = fmaxf(red[tid], red[tid+s]); __syncthreads(); }
    float scale = fmaxf(red[0]/127.f, 1e-8f);
    float rs = 1.f/scale;
    if (tid == 0) scl[row] = scale;
    for (int s = tid; s < 288; s += 256) {
        int i4 = s*4;
        f32x4 y = *(const f32x4*)&Ys[i4];
        ushort4v o;
        #pragma unroll
        for (int c = 0; c < 4; ++c) {
            float v = rintf(y[c]*rs);
            v = fminf(fmaxf(v, -128.f), 127.f);
            o[c] = (unsigned short)bf16rne(v);
        }
        *(ushort4v*)&dst[(size_t)row*DD + i4] = o;
    }
}

// ---------------- merged weight kron: z=0 Wq->4bit, z=1 Wk->4bit, z=2 Wv->fp32 ----------------
__global__ __launch_bounds__(256) void kron_w3(const float* __restrict__ Wq, const float* __restrict__ Wk,
                                               const float* __restrict__ Wv,
                                               unsigned short* __restrict__ Wq_b, unsigned short* __restrict__ Wk_b,
                                               float* __restrict__ Wvm,
                                               float* __restrict__ s_wq, float* __restrict__ s_wk,
                                               const float* __restrict__ P, const float* __restrict__ Q,
                                               const float* __restrict__ diag)
{
    __shared__ float Xs[LL*RR], T1[LL*RR], Ps[LL*LL], Qs[RR*RR], Ys[LL*RR], red[256];
    int z = blockIdx.x / DD;
    int row = blockIdx.x % DD;
    const float* src = (z == 0) ? Wq : (z == 1) ? Wk : Wv;
    int tid = threadIdx.x;
    const float* sr = src + (size_t)row*DD;
    for (int i = tid; i < LL*LL; i += 256) Ps[i] = P[i];
    for (int i = tid; i < RR*RR; i += 256) Qs[i] = Q[i];
    for (int i = tid; i < DD; i += 256) Xs[i] = sr[i]*(1.0f/diag[i]);
    __syncthreads();
    for (int s = tid; s < 288; s += 256) {
        int p = s / 9, r4 = (s % 9)*4;
        f32x4 acc = {0.f,0.f,0.f,0.f};
        #pragma unroll 8
        for (int l = 0; l < LL; ++l) {
            float a = Ps[l*LL + p];
            f32x4 x = *(const f32x4*)&Xs[l*RR + r4];
            acc += a*x;
        }
        *(f32x4*)&T1[p*RR + r4] = acc;
    }
    __syncthreads();
    float lmax = 0.f;
    for (int s = tid; s < 288; s += 256) {
        int p = s / 9, q4 = (s % 9)*4;
        f32x4 acc = {0.f,0.f,0.f,0.f};
        #pragma unroll 9
        for (int r = 0; r < RR; ++r) {
            float t = T1[p*RR + r];
            f32x4 qv = *(const f32x4*)&Qs[r*RR + q4];
            acc += t*qv;
        }
        *(f32x4*)&Ys[p*RR + q4] = acc;
        lmax = fmaxf(lmax, fmaxf(fmaxf(fabsf(acc[0]), fabsf(acc[1])), fmaxf(fabsf(acc[2]), fabsf(acc[3]))));
    }
    if (z == 2) {
        __syncthreads();
        for (int s = tid; s < 288; s += 256) {
            int i4 = s*4;
            *(f32x4*)&Wvm[(size_t)row*DD + i4] = *(const f32x4*)&Ys[i4];
        }
        return;
    }
    red[tid] = lmax; __syncthreads();
    for (int s = 128; s > 0; s >>= 1) { if (tid < s) red[tid] = fmaxf(red[tid], red[tid+s]); __syncthreads(); }
    float scale = fmaxf(red[0]/7.f, 1e-8f);
    float rs = 1.f/scale;
    float* scl = (z == 0) ? s_wq : s_wk;
    unsigned short* dst = (z == 0) ? Wq_b : Wk_b;
    if (tid == 0) scl[row] = scale;
    for (int s = tid; s < 288; s += 256) {
        int i4 = s*4;
        f32x4 y = *(const f32x4*)&Ys[i4];
        ushort4v o;
        #pragma unroll
        for (int c = 0; c < 4; ++c) {
            float v = rintf(y[c]*rs);
            v = fminf(fmaxf(v, -8.f), 7.f);
            o[c] = (unsigned short)bf16rne(v);
        }
        *(ushort4v*)&dst[(size_t)row*DD + i4] = o;
    }
}

// ---------------- Wv out-channel fold + fused 4-bit quant ----------------
__global__ __launch_bounds__(256) void wv_fold_q(const float* __restrict__ tmp, const float* __restrict__ vc,
                                                 const float* __restrict__ bv, unsigned short* __restrict__ dst,
                                                 float* __restrict__ scl, float* __restrict__ bvt)
{
    int he = blockIdx.x;
    int h = he / HD, e = he % HD;
    __shared__ float vcol[HD], Ys[DD], red[256];
    int tid = threadIdx.x;
    if (tid < HD) vcol[tid] = vc[tid*HD + e];
    __syncthreads();
    const float* base = tmp + (size_t)h*HD*DD;
    float lmax = 0.f;
    for (int i = tid; i < DD; i += 256) {
        float acc = 0.f;
        #pragma unroll 8
        for (int d = 0; d < HD; ++d) acc += base[(size_t)d*DD + i]*vcol[d];
        Ys[i] = acc;
        lmax = fmaxf(lmax, fabsf(acc));
    }
    red[tid] = lmax; __syncthreads();
    for (int s = 128; s > 0; s >>= 1) { if (tid < s) red[tid] = fmaxf(red[tid], red[tid+s]); __syncthreads(); }
    float scale = fmaxf(red[0]/7.f, 1e-8f);
    float rs = 1.f/scale;
    if (tid == 0) {
        scl[he] = scale;
        float acc = 0.f;
        for (int d = 0; d < HD; ++d) acc += bv[h*HD + d]*vcol[d];
        bvt[he] = acc;
    }
    for (int i = tid; i < DD; i += 256) {
        float v = rintf(Ys[i]*rs);
        v = fminf(fmaxf(v, -8.f), 7.f);
        dst[(size_t)he*DD + i] = (unsigned short)bf16rne(v);
    }
}

// ---------------- Wo transform + fused 4-bit quant ----------------
__global__ __launch_bounds__(256) void wo_trans_q(const float* __restrict__ Wo, const float* __restrict__ iO,
                                                  const float* __restrict__ iV, unsigned short* __restrict__ dst,
                                                  float* __restrict__ scl)
{
    __shared__ float M[HH*HD], T1[HH*HD], iOs[HH*HH], iVs[HD*HD], Ys[DD], red[256];
    int row = blockIdx.x, tid = threadIdx.x;
    for (int i = tid; i < DD; i += 256) M[i] = Wo[(size_t)row*DD + i];
    for (int i = tid; i < HH*HH; i += 256) iOs[i] = iO[i];
    for (int i = tid; i < HD*HD; i += 256) iVs[i] = iV[i];
    __syncthreads();
    for (int i = tid; i < DD; i += 256) {
        int h = i / HD, d = i % HD;
        float a = 0.f;
        #pragma unroll
        for (int g = 0; g < HH; ++g) a += iOs[h*HH + g]*M[g*HD + d];
        T1[i] = a;
    }
    __syncthreads();
    float lmax = 0.f;
    for (int i = tid; i < DD; i += 256) {
        int h = i / HD, e = i % HD;
        float a = 0.f;
        #pragma unroll 8
        for (int d = 0; d < HD; ++d) a += T1[h*HD + d]*iVs[e*HD + d];
        Ys[i] = a;
        lmax = fmaxf(lmax, fabsf(a));
    }
    red[tid] = lmax; __syncthreads();
    for (int s = 128; s > 0; s >>= 1) { if (tid < s) red[tid] = fmaxf(red[tid], red[tid+s]); __syncthreads(); }
    float scale = fmaxf(red[0]/7.f, 1e-8f);
    float rs = 1.f/scale;
    if (tid == 0) scl[row] = scale;
    for (int i = tid; i < DD; i += 256) {
        float v = rintf(Ys[i]*rs);
        v = fminf(fmaxf(v, -8.f), 7.f);
        dst[(size_t)row*DD + i] = (unsigned short)bf16rne(v);
    }
}

// ---------------- double-buffered MFMA GEMM K-loop (T3/T4-lite) ----------------
// smem: As = smem[0..8191] (2 x 4096), Bs = smem[8192..16383] (2 x 4096)
#define GEMM_STAGE(As, Bs, bufo, k0_, Xb, Wb, tid) { \
    _Pragma("unroll") for (int j_ = 0; j_ < 2; ++j_) { \
        int idx_ = (tid) + j_*256; \
        int row_ = idx_ >> 2, pp_ = idx_ & 3; \
        int s_ = pp_ ^ ((row_ >> 1) & 3); \
        async_ld16(&As[(bufo) + idx_*8], (Xb) + (size_t)row_*DD + (k0_) + s_*8); \
        async_ld16(&Bs[(bufo) + idx_*8], (Wb) + (size_t)row_*DD + (k0_) + s_*8); \
    } }

__device__ __forceinline__ void gemm_body_db(const unsigned short* __restrict__ Xb, const unsigned short* __restrict__ Wb,
                                             unsigned short* As, unsigned short* Bs, f32x4 (&acc)[4][4],
                                             int wr, int wc, int lr, int lg)
{
    int tid = threadIdx.x;
    GEMM_STAGE(As, Bs, 0, 0, Xb, Wb, tid);
    int cur = 0;
    for (int t = 0; t < 36; ++t) {
        if (t < 35) {
            GEMM_STAGE(As, Bs, (cur^1)*4096, (t+1)*32, Xb, Wb, tid);
            asm volatile("s_waitcnt vmcnt(4)" ::: "memory");     // old 4 stage-loads done; new 4 in flight
        } else {
            asm volatile("s_waitcnt vmcnt(0)" ::: "memory");
        }
        __builtin_amdgcn_sched_barrier(0);
        __builtin_amdgcn_s_barrier();
        const unsigned short* Ab = &As[cur*4096];
        const unsigned short* Bb = &Bs[cur*4096];
        short8 a[4], bfr[4];
        #pragma unroll
        for (int fr = 0; fr < 4; ++fr) {
            int row = wr*64 + fr*16 + lr;
            a[fr] = *(const short8*)(&Ab[row*32 + (lg ^ ((row>>1)&3))*8]);
        }
        #pragma unroll
        for (int fc = 0; fc < 4; ++fc) {
            int row = wc*64 + fc*16 + lr;
            bfr[fc] = *(const short8*)(&Bb[row*32 + (lg ^ ((row>>1)&3))*8]);
        }
        #pragma unroll
        for (int fr = 0; fr < 4; ++fr)
            #pragma unroll
            for (int fc = 0; fc < 4; ++fc)
                acc[fr][fc] = __builtin_amdgcn_mfma_f32_16x16x32_bf16(a[fr], bfr[fc], acc[fr][fc], 0, 0, 0);
        __builtin_amdgcn_s_barrier();                            // reads done before buf overwrite
        cur ^= 1;
    }
}

// ---------------- merged q/k/v projection GEMM; q/k token-major, V written TRANSPOSED ----------------
__global__ __launch_bounds__(256) void gemm_qkv(const unsigned short* __restrict__ X,
                                                const unsigned short* __restrict__ Wq_b,
                                                const unsigned short* __restrict__ Wk_b,
                                                const unsigned short* __restrict__ Wv_b,
                                                const float* __restrict__ sx, const float* __restrict__ ws_all,
                                                const float* __restrict__ bq, const float* __restrict__ bk,
                                                const float* __restrict__ bvt,
                                                unsigned short* __restrict__ qb, unsigned short* __restrict__ kb,
                                                unsigned short* __restrict__ vT)
{
    __shared__ __align__(16) unsigned short smem[16384];
    unsigned short* As = smem;
    unsigned short* Bs = smem + 8192;
    int lin = blockIdx.x;
    int nl = (lin & 7)*216 + (lin >> 3);    // XCD-contiguous chunks (1728 % 8 == 0)
    int z = nl / 576;
    int rem = nl - z*576;
    int bm = rem / 9, bn = rem - bm*9;
    const unsigned short* W = (z == 0) ? Wq_b : (z == 1) ? Wk_b : Wv_b;
    const float* sw_ = ws_all + (size_t)z*1152;
    const float* bias = (z == 0) ? bq : (z == 1) ? bk : bvt;
    int tid = threadIdx.x;
    int wave = tid >> 6, lane = tid & 63;
    int wr = wave >> 1, wc = wave & 1;
    int lr = lane & 15, lg = lane >> 4;
    f32x4 acc[4][4];
    #pragma unroll
    for (int i = 0; i < 4; ++i)
        #pragma unroll
        for (int j = 0; j < 4; ++j)
            #pragma unroll
            for (int e = 0; e < 4; ++e) acc[i][j][e] = 0.f;
    gemm_body_db(X + (size_t)bm*128*DD, W + (size_t)bn*128*DD, As, Bs, acc, wr, wc, lr, lg);
    float swn[4], bnv[4];
    #pragma unroll
    for (int fc = 0; fc < 4; ++fc) {
        int n = bn*128 + wc*64 + fc*16 + lr;
        swn[fc] = sw_[n]; bnv[fc] = bias[n];
    }
    if (z <= 1) {
        unsigned short* outQ = (z == 0) ? qb : kb;
        #pragma unroll
        for (int c = 0; c < 2; ++c) {
            __syncthreads();
            if (wr == c) {
                #pragma unroll
                for (int fr = 0; fr < 4; ++fr) {
                    #pragma unroll
                    for (int j = 0; j < 4; ++j) {
                        int rloc = fr*16 + lg*4 + j;
                        float sxm = sx[bm*128 + c*64 + rloc];
                        #pragma unroll
                        for (int fc = 0; fc < 4; ++fc) {
                            int cloc = wc*64 + fc*16 + lr;
                            float v = acc[fr][fc][j]*sxm*swn[fc] + bnv[fc];
                            smem[rloc*128 + cloc] = (unsigned short)bf16rne(v);
                        }
                    }
                }
            }
            __syncthreads();
            #pragma unroll
            for (int it = 0; it < 4; ++it) {
                int idx = tid + it*256;
                int row = idx >> 4, seg = idx & 15;
                size_t g = ((size_t)(bm*128 + c*64 + row))*DD + bn*128 + seg*8;
                *(short8*)(&outQ[g]) = *(const short8*)(&smem[row*128 + seg*8]);
            }
        }
    } else {
        // V: write directly transposed -> vT[(b*16+h)*96 + hd][S], stride-130 LDS tile
        int b = bm >> 3;
        int srow = (bm & 7)*128;
        #pragma unroll
        for (int c = 0; c < 2; ++c) {
            __syncthreads();
            if (wr == c) {
                #pragma unroll
                for (int fr = 0; fr < 4; ++fr) {
                    #pragma unroll
                    for (int j = 0; j < 4; ++j) {
                        int rloc = fr*16 + lg*4 + j;
                        float sxm = sx[bm*128 + c*64 + rloc];
                        #pragma unroll
                        for (int fc = 0; fc < 4; ++fc) {
                            int cloc = wc*64 + fc*16 + lr;
                            float v = acc[fr][fc][j]*sxm*swn[fc] + bnv[fc];
                            smem[rloc*130 + cloc] = (unsigned short)bf16rne(v);
                        }
                    }
                }
            }
            __syncthreads();
            #pragma unroll
            for (int it = 0; it < 4; ++it) {
                int idx = tid + it*256;          // 0..1023 = 128 cols x 8 tok8-groups
                int tok8 = idx & 7, cloc = idx >> 3;
                int n = bn*128 + cloc;
                int h = n / 72, hd = n - h*72;
                unsigned short tmp[8];
                #pragma unroll
                for (int kk = 0; kk < 8; ++kk) tmp[kk] = smem[(tok8*8 + kk)*130 + cloc];
                size_t g = ((size_t)((b*HH + h)*PD + hd))*SS + srow + c*64 + tok8*8;
                *(short8*)(&vT[g]) = *(const short8*)tmp;
            }
        }
    }
}

// ---------------- output projection GEMM (fp32 out), XCD-swizzled, double-buffered ----------------
__global__ __launch_bounds__(256) void gemm_out(const unsigned short* __restrict__ X, const unsigned short* __restrict__ W,
                                                const float* __restrict__ sx, const float* __restrict__ sw_,
                                                const float* __restrict__ bias, float* __restrict__ outF)
{
    __shared__ __align__(16) unsigned short smem[16384];
    unsigned short* As = smem;
    unsigned short* Bs = smem + 8192;
    int lin = blockIdx.x;
    int nl = (lin & 7)*72 + (lin >> 3);
    int bm = nl / 9, bn = nl - bm*9;
    int tid = threadIdx.x;
    int wave = tid >> 6, lane = tid & 63;
    int wr = wave >> 1, wc = wave & 1;
    int lr = lane & 15, lg = lane >> 4;
    f32x4 acc[4][4];
    #pragma unroll
    for (int i = 0; i < 4; ++i)
        #pragma unroll
        for (int j = 0; j < 4; ++j)
            #pragma unroll
            for (int e = 0; e < 4; ++e) acc[i][j][e] = 0.f;
    gemm_body_db(X + (size_t)bm*128*DD, W + (size_t)bn*128*DD, As, Bs, acc, wr, wc, lr, lg);
    #pragma unroll
    for (int fc = 0; fc < 4; ++fc) {
        int n = bn*128 + wc*64 + fc*16 + lr;
        float swn = sw_[n], bnv = bias[n];
        #pragma unroll
        for (int fr = 0; fr < 4; ++fr) {
            #pragma unroll
            for (int j = 0; j < 4; ++j) {
                int mrow = bm*128 + wr*64 + fr*16 + lg*4 + j;
                outF[(size_t)mrow*DD + n] = acc[fr][fc][j]*sx[mrow]*swn + bnv;
            }
        }
    }
}

// ---------------- MFMA flash attention, token-major q/k, transposed V, XCD-swizzled ----------------
__global__ __launch_bounds__(256) void attn_mfma(const unsigned short* __restrict__ q, const unsigned short* __restrict__ k,
                                                 const unsigned short* __restrict__ vT, float* __restrict__ ctx)
{
    __shared__ unsigned short Kl[64*128];
    __shared__ unsigned short Vl[96*64];
    int lin = blockIdx.x;
    int nl = (lin & 7)*128 + (lin >> 3);
    int bh = nl >> 3;
    int qblk = nl & 7;
    int tid = threadIdx.x;
    int wave = tid >> 6, lane = tid & 63;
    int lq = lane & 31, half = lane >> 5;
    int b = bh >> 4, h = bh & 15;
    const unsigned short* qrow = q + ((size_t)(b*SS + qblk*128 + wave*32 + lq))*DD + h*HD;
    const unsigned short* kbb  = k + (size_t)b*SS*DD + h*HD;
    const unsigned short* vtb  = vT + (size_t)bh*PD*SS;
    short8 zero8 = {0,0,0,0,0,0,0,0};
    short8 qf[6];
    #pragma unroll
    for (int ks = 0; ks < 4; ++ks)
        qf[ks] = *(const short8*)(qrow + ks*16 + half*8);
    qf[4] = (half == 0) ? *(const short8*)(qrow + 64) : zero8;
    qf[5] = zero8;
    // pre-zero pad slots once: K slots s=9..11, V rows d>=72 (rewritten never)
    for (int idx = tid; idx < 192; idx += 256) {
        int row = idx / 3, s = 9 + idx % 3;
        *(short8*)(&Kl[row*128 + (s ^ (row & 7))*8]) = zero8;
    }
    for (int idx = tid; idx < 192; idx += 256) {
        int d = 72 + (idx >> 3), p = idx & 7;
        *(short8*)(&Vl[d*64 + p*8]) = zero8;
    }
    f32x16 O0, O1, O2;
    #pragma unroll
    for (int r = 0; r < 16; ++r) { O0[r] = 0.f; O1[r] = 0.f; O2[r] = 0.f; }
    float m = -1e30f, l = 0.f;
    for (int t0 = 0; t0 < SS; t0 += 64) {
        __syncthreads();
        // stage K tile: 64 keys x 9 real slots, swizzled
        for (int idx = tid; idx < 576; idx += 256) {
            int row = idx / 9, s = idx % 9;
            short8 val = *(const short8*)(kbb + (size_t)(t0 + row)*DD + s*8);
            *(short8*)(&Kl[row*128 + (s ^ (row & 7))*8]) = val;
        }
        // stage V^T tile: 72 real d x 8 slots, swizzled
        for (int idx = tid; idx < 576; idx += 256) {
            int d = idx >> 3, p = idx & 7;
            int s = p ^ (d & 7);
            short8 val = *(const short8*)(vtb + (size_t)d*SS + t0 + s*8);
            *(short8*)(&Vl[d*64 + p*8]) = val;
        }
        __syncthreads();
        #pragma unroll
        for (int sub = 0; sub < 2; ++sub) {
            f32x16 sacc;
            #pragma unroll
            for (int r = 0; r < 16; ++r) sacc[r] = 0.f;
            __builtin_amdgcn_s_setprio(1);
            #pragma unroll
            for (int ks = 0; ks < 6; ++ks) {
                int key = sub*32 + lq;
                short8 kf = *(const short8*)(&Kl[key*128 + (((ks*2 + half) ^ (lq & 7)))*8]);
                sacc = __builtin_amdgcn_mfma_f32_32x32x16_bf16(kf, qf[ks], sacc, 0, 0, 0);
            }
            __builtin_amdgcn_s_setprio(0);
            float pa = fmaxf(fmaxf(sacc[0], sacc[1]), fmaxf(sacc[2], sacc[3]));
            float pb = fmaxf(fmaxf(sacc[4], sacc[5]), fmaxf(sacc[6], sacc[7]));
            float pc = fmaxf(fmaxf(sacc[8], sacc[9]), fmaxf(sacc[10], sacc[11]));
            float pd = fmaxf(fmaxf(sacc[12], sacc[13]), fmaxf(sacc[14], sacc[15]));
            float pmax = fmaxf(fmaxf(pa, pb), fmaxf(pc, pd));
            pmax = fmaxf(pmax, __shfl_xor(pmax, 32));
            if (!__all(pmax - m <= 8.0f)) {
                float mn = fmaxf(m, pmax);
                float corr = __expf(m - mn);
                m = mn;
                l *= corr;
                #pragma unroll
                for (int r = 0; r < 16; ++r) {
                    int rowq = (r&3) + 8*(r>>2) + 4*half;
                    float cr = __shfl(corr, rowq);
                    O0[r] *= cr; O1[r] *= cr; O2[r] *= cr;
                }
            }
            float p[16]; float ls = 0.f;
            #pragma unroll
            for (int r = 0; r < 16; ++r) { p[r] = __expf(sacc[r] - m); ls += p[r]; }
            ls += __shfl_xor(ls, 32);
            l += ls;
            unsigned pk[8], sw[8];
            #pragma unroll
            for (int j2 = 0; j2 < 8; ++j2) pk[j2] = cvtpk(p[2*j2], p[2*j2+1]);
            #pragma unroll
            for (int j2 = 0; j2 < 8; ++j2) sw[j2] = __shfl_xor(pk[j2], 32);
            short8 A0 = half ? mk8(sw[2], sw[3], pk[2], pk[3]) : mk8(pk[0], pk[1], sw[0], sw[1]);
            short8 A1 = half ? mk8(sw[6], sw[7], pk[6], pk[7]) : mk8(pk[4], pk[5], sw[4], sw[5]);
            __builtin_amdgcn_s_setprio(1);
            #pragma unroll
            for (int dt = 0; dt < 3; ++dt) {
                int d = dt*32 + lq;
                short8 vf0 = *(const short8*)(&Vl[d*64 + (((sub*4 + half) ^ (d & 7)))*8]);
                short8 vf1 = *(const short8*)(&Vl[d*64 + (((sub*4 + 2 + half) ^ (d & 7)))*8]);
                if (dt == 0) { O0 = __builtin_amdgcn_mfma_f32_32x32x16_bf16(A0, vf0, O0, 0,0,0);
                               O0 = __builtin_amdgcn_mfma_f32_32x32x16_bf16(A1, vf1, O0, 0,0,0); }
                if (dt == 1) { O1 = __builtin_amdgcn_mfma_f32_32x32x16_bf16(A0, vf0, O1, 0,0,0);
                               O1 = __builtin_amdgcn_mfma_f32_32x32x16_bf16(A1, vf1, O1, 0,0,0); }
                if (dt == 2) { O2 = __builtin_amdgcn_mfma_f32_32x32x16_bf16(A0, vf0, O2, 0,0,0);
                               O2 = __builtin_amdgcn_mfma_f32_32x32x16_bf16(A1, vf1, O2, 0,0,0); }
            }
            __builtin_amdgcn_s_setprio(0);
        }
    }
    float linv = 1.f / l;
    #pragma unroll
    for (int r = 0; r < 16; ++r) {
        int rowq = (r&3) + 8*(r>>2) + 4*half;
        float lr2 = __shfl(linv, rowq);
        int s = qblk*128 + wave*32 + rowq;
        size_t base = ((size_t)(b*SS + s))*DD + h*HD;
        ctx[base + lq]      = O0[r]*lr2;
        ctx[base + 32 + lq] = O1[r]*lr2;
        if (lq < 8) ctx[base + 64 + lq] = O2[r]*lr2;
    }
}

// ---------------- head mix + 8-bit quant ----------------
__global__ __launch_bounds__(256) void octx_fq_q(const float* __restrict__ ctx, const float* __restrict__ o_mat,
                                                 unsigned short* __restrict__ out, float* __restrict__ scl)
{
    __shared__ float ct[DD], Ys[DD], om[HH*HH], red[256];
    int t = blockIdx.x, tid = threadIdx.x;
    for (int i = tid; i < DD; i += 256) ct[i] = ctx[(size_t)t*DD + i];
    for (int i = tid; i < HH*HH; i += 256) om[i] = o_mat[i];
    __syncthreads();
    float lmax = 0.f;
    for (int s = tid; s < 288; s += 256) {
        int h = s / 18, d4 = (s % 18)*4;
        f32x4 acc = {0.f,0.f,0.f,0.f};
        #pragma unroll
        for (int g = 0; g < HH; ++g) {
            float o = om[g*HH + h];
            f32x4 c = *(const f32x4*)&ct[g*HD + d4];
            acc += o*c;
        }
        *(f32x4*)&Ys[h*HD + d4] = acc;
        lmax = fmaxf(lmax, fmaxf(fmaxf(fabsf(acc[0]), fabsf(acc[1])), fmaxf(fabsf(acc[2]), fabsf(acc[3]))));
    }
    red[tid] = lmax; __syncthreads();
    for (int s = 128; s > 0; s >>= 1) { if (tid < s) red[tid] = fmaxf(red[tid], red[tid+s]); __syncthreads(); }
    float scale = fmaxf(red[0]/127.f, 1e-8f);
    float rs = 1.f/scale;
    if (tid == 0) scl[t] = scale;
    for (int s = tid; s < 288; s += 256) {
        int i4 = s*4;
        f32x4 y = *(const f32x4*)&Ys[i4];
        ushort4v o;
        #pragma unroll
        for (int c = 0; c < 4; ++c) {
            float v = rintf(y[c]*rs);
            v = fminf(fmaxf(v, -128.f), 127.f);
            o[c] = (unsigned short)bf16rne(v);
        }
        *(ushort4v*)&out[(size_t)t*DD + i4] = o;
    }
}

extern "C" void kernel_launch(void* const* d_in, const int* in_sizes, int n_in,
                              void* d_out, int out_size, void* d_ws, size_t ws_size,
                              hipStream_t stream)
{
    const float* hidden = (const float*)d_in[0];
    const float* Wq = (const float*)d_in[1];  const float* bq = (const float*)d_in[2];
    const float* Wk = (const float*)d_in[3];  const float* bk = (const float*)d_in[4];
    const float* Wv = (const float*)d_in[5];  const float* bv = (const float*)d_in[6];
    const float* Wo = (const float*)d_in[7];  const float* bo = (const float*)d_in[8];
    const float* lnA = (const float*)d_in[9];
    const float* lnB = (const float*)d_in[10];
    const float* ln_diag = (const float*)d_in[11];
    const float* vc = (const float*)d_in[12];
    const float* o_mat = (const float*)d_in[13];
    float* ws = (float*)d_ws;
    float* out = (float*)d_out;
    char* wsb = (char*)d_ws;

    float* iAT  = ws + F_IAT;
    float* iBT  = ws + F_IBT;
    float* iO   = ws + F_IO;
    float* iV   = ws + F_IV;
    float* bvt  = ws + F_BVT;
    float* s_x  = ws + F_SX;
    float* s_wq = ws + F_SWQ;   // s_wq/s_wk/s_wv contiguous (ws_all)
    float* s_wk = ws + F_SWK;
    float* s_wv = ws + F_SWV;
    float* s_wo = ws + F_SWO;
    float* s_ct = ws + F_SCTX;

    float* slot = (float*)(wsb + B_R1);
    float* Wvm  = slot + 2*WSLOT;
    float* ctxf = slot;

    unsigned short* Wq_b = (unsigned short*)(wsb + B_WB);
    unsigned short* Wk_b = Wq_b + WSLOT;
    unsigned short* Wv_b = Wq_b + 2*WSLOT;
    unsigned short* Wo_b = Wq_b + 3*WSLOT;
    unsigned short* x_b  = (unsigned short*)(wsb + B_XB);
    unsigned short* ctx_b = x_b;
    unsigned short* qb = (unsigned short*)(wsb + B_QB);
    unsigned short* kb = (unsigned short*)(wsb + B_KB);
    unsigned short* vT = (unsigned short*)(wsb + B_VT);

    // 1. small inversions
    invert_kernel<<<4, 128, 0, stream>>>(lnA, lnB, o_mat, vc, ws);
    // 2. activation kron + 8-bit quant
    kron_act_q<<<NTOK, 256, 0, stream>>>(hidden, x_b, s_x, lnA, lnB, ln_diag);
    // 3. merged weight kron (Wq/Wk quantized, Wv fp32 pre-fold)
    kron_w3<<<3*DD, 256, 0, stream>>>(Wq, Wk, Wv, Wq_b, Wk_b, Wvm, s_wq, s_wk, iAT, iBT, ln_diag);
    wv_fold_q<<<DD, 256, 0, stream>>>(Wvm, vc, bv, Wv_b, s_wv, bvt);
    wo_trans_q<<<DD, 256, 0, stream>>>(Wo, iO, iV, Wo_b, s_wo);
    // 4. merged q/k/v projections (dbuf MFMA); q/k token-major, V written transposed
    gemm_qkv<<<dim3(1728), 256, 0, stream>>>(x_b, Wq_b, Wk_b, Wv_b, s_x, s_wq, bq, bk, bvt, qb, kb, vT);
    // 5. flash attention (XCD-swizzled)
    attn_mfma<<<dim3(1024), 256, 0, stream>>>(qb, kb, vT, ctxf);
    // 6. head-mix + 8-bit quant
    octx_fq_q<<<NTOK, 256, 0, stream>>>(ctxf, o_mat, ctx_b, s_ct);
    // 7. output projection (fp32 out, dbuf MFMA)
    gemm_out<<<dim3(576), 256, 0, stream>>>(ctx_b, Wo_b, s_ct, s_wo, bo, out);
}